// Round 3
// baseline (132.457 us; speedup 1.0000x reference)
//
#include <hip/hip_runtime.h>
#include <math.h>

#define BB 8
#define NN 256
#define XHIN 9
#define XHHID 64
#define POSHID 192
#define TS 16                       // node tile size
#define NT (NN / TS)                // 16 tiles
#define NPAIR (NT * (NT + 1) / 2)   // 136 unordered tile-pairs
#define RPB 4                       // rows per block in out_kernel
#define FREQC 0.10381025296523007f  // log2(100)/64

// ---------------------------------------------------------------------------
// K1: blocks 0..7: per-batch masked mean removal (centered x SoA + count).
//     blocks 8..71: zero ws_S (262144 floats) — workspace is re-poisoned
//     every iteration, so the accumulator must be cleared in-band.
// ---------------------------------------------------------------------------
__global__ __launch_bounds__(256) void mean_zero_kernel(
    const float* __restrict__ xh, const float* __restrict__ mask,
    float* __restrict__ ws_xc, float* __restrict__ ws_cnt,
    float4* __restrict__ ws_S4)
{
  if (blockIdx.x >= BB) {                        // zeroing blocks
    const int base = (blockIdx.x - BB) * 1024 + threadIdx.x;
    #pragma unroll
    for (int k = 0; k < 4; ++k)
      ws_S4[base + k * 256] = make_float4(0.f, 0.f, 0.f, 0.f);
    return;
  }
  const int b = blockIdx.x;
  const int n = threadIdx.x;

  const float* p = xh + (b * NN + n) * XHIN;
  const float x0 = p[0], x1 = p[1], x2 = p[2];
  const float m = mask[b * NN + n];

  float a0 = x0 * m, a1 = x1 * m, a2 = x2 * m, a3 = m;
  #pragma unroll
  for (int off = 32; off > 0; off >>= 1) {
    a0 += __shfl_down(a0, off, 64);
    a1 += __shfl_down(a1, off, 64);
    a2 += __shfl_down(a2, off, 64);
    a3 += __shfl_down(a3, off, 64);
  }
  __shared__ float red[4][4];
  const int lane = n & 63, wv = n >> 6;
  if (lane == 0) { red[wv][0] = a0; red[wv][1] = a1; red[wv][2] = a2; red[wv][3] = a3; }
  __syncthreads();

  const float s0 = red[0][0] + red[1][0] + red[2][0] + red[3][0];
  const float s1 = red[0][1] + red[1][1] + red[2][1] + red[3][1];
  const float s2 = red[0][2] + red[1][2] + red[2][2] + red[3][2];
  const float cnt = red[0][3] + red[1][3] + red[2][3] + red[3][3];
  const float inv = 1.0f / cnt;

  ws_xc[(b * 3 + 0) * NN + n] = (x0 - s0 * inv) * m;
  ws_xc[(b * 3 + 1) * NN + n] = (x1 - s1 * inv) * m;
  ws_xc[(b * 3 + 2) * NN + n] = (x2 - s2 * inv) * m;
  if (n == 0) ws_cnt[b] = cnt;
}

// ---------------------------------------------------------------------------
// K2: symmetric tile-pair kernel. Block = (batch, unordered tile-pair (I,J)).
// Each sin/cos evaluation at d_ij feeds BOTH row i (weight m_j, registers)
// and row j (weight m_i, LDS partial) — 0.53x the trans work of the full
// ordered sweep. Accumulation into ws_S via f32 atomicAdd.
// Thread layout phase B: (f = tid&63, g = tid>>6); thread owns freq f and
// i-rows {4g..4g+3}, loops all 16 j. d_s stored [j][i] so the 4 i-cells
// arrive as one b128 broadcast.
// ---------------------------------------------------------------------------
__global__ __launch_bounds__(256) void pairs_kernel(
    const float* __restrict__ ws_xc, const float* __restrict__ mask,
    float* __restrict__ ws_S)
{
  const int b = blockIdx.x / NPAIR;
  int p = blockIdx.x % NPAIR;
  int I = 0;
  while (p >= NT - I) { p -= NT - I; ++I; }      // uniform, <=16 iters
  const int J = I + p;
  const bool diag = (I == J);
  const int tid = threadIdx.x;

  __shared__ float xs[2][3][TS];                 // coords of tile I(0)/J(1)
  __shared__ float ms[2][TS];                    // masks
  __shared__ __align__(16) float d_s[TS][TS];    // [j][i]
  __shared__ float Sj[TS][128];                  // j-side partials

  if (tid < 96) {
    const int t = tid / 48, r = tid % 48, c = r / 16, n = r % 16;
    xs[t][c][n] = ws_xc[(b * 3 + c) * NN + (t ? J : I) * TS + n];
  }
  if (tid < 32) {
    const int t = tid >> 4, n = tid & 15;
    ms[t][n] = mask[b * NN + (t ? J : I) * TS + n];
  }
  {
    float4* z = (float4*)Sj;                     // 512 float4
    z[tid] = make_float4(0.f, 0.f, 0.f, 0.f);
    z[tid + 256] = make_float4(0.f, 0.f, 0.f, 0.f);
  }
  __syncthreads();
  {
    const int i = tid & 15, j = tid >> 4;        // one cell per thread
    const float dx = xs[0][0][i] - xs[1][0][j];
    const float dy = xs[0][1][i] - xs[1][1][j];
    const float dz = xs[0][2][i] - xs[1][2][j];
    d_s[j][i] = sqrtf(fmaf(dx, dx, fmaf(dy, dy, dz * dz)) + 1e-12f);
  }
  __syncthreads();

  const int f = tid & 63, g = tid >> 6;
  const float freq = __builtin_exp2f((float)f * FREQC);  // 100^(f/64)
  float si0 = 0.f, si1 = 0.f, si2 = 0.f, si3 = 0.f;
  float ci0 = 0.f, ci1 = 0.f, ci2 = 0.f, ci3 = 0.f;
  const float mA0 = ms[0][g * 4 + 0], mA1 = ms[0][g * 4 + 1];
  const float mA2 = ms[0][g * 4 + 2], mA3 = ms[0][g * 4 + 3];

  #pragma unroll 4
  for (int j = 0; j < TS; ++j) {
    const float4 d4 = *(const float4*)&d_s[j][g * 4];    // b128 broadcast
    const float mj = ms[1][j];
    float sj = 0.f, cj = 0.f;
    {
      const float rv = __builtin_amdgcn_fractf(d4.x * freq);
      const float s_ = __builtin_amdgcn_sinf(rv);
      const float c_ = __builtin_amdgcn_cosf(rv);
      si0 = fmaf(mj, s_, si0); ci0 = fmaf(mj, c_, ci0);
      sj = fmaf(mA0, s_, sj);  cj = fmaf(mA0, c_, cj);
    }
    {
      const float rv = __builtin_amdgcn_fractf(d4.y * freq);
      const float s_ = __builtin_amdgcn_sinf(rv);
      const float c_ = __builtin_amdgcn_cosf(rv);
      si1 = fmaf(mj, s_, si1); ci1 = fmaf(mj, c_, ci1);
      sj = fmaf(mA1, s_, sj);  cj = fmaf(mA1, c_, cj);
    }
    {
      const float rv = __builtin_amdgcn_fractf(d4.z * freq);
      const float s_ = __builtin_amdgcn_sinf(rv);
      const float c_ = __builtin_amdgcn_cosf(rv);
      si2 = fmaf(mj, s_, si2); ci2 = fmaf(mj, c_, ci2);
      sj = fmaf(mA2, s_, sj);  cj = fmaf(mA2, c_, cj);
    }
    {
      const float rv = __builtin_amdgcn_fractf(d4.w * freq);
      const float s_ = __builtin_amdgcn_sinf(rv);
      const float c_ = __builtin_amdgcn_cosf(rv);
      si3 = fmaf(mj, s_, si3); ci3 = fmaf(mj, c_, ci3);
      sj = fmaf(mA3, s_, sj);  cj = fmaf(mA3, c_, cj);
    }
    if (!diag) {
      atomicAdd(&Sj[j][f], sj);
      atomicAdd(&Sj[j][64 + f], cj);
    }
  }

  // i-side: direct to global (no intra-block collisions: unique (g,r,f))
  {
    const int row = b * NN + I * TS + g * 4;
    atomicAdd(&ws_S[(size_t)(row + 0) * 128 + f], si0);
    atomicAdd(&ws_S[(size_t)(row + 0) * 128 + 64 + f], ci0);
    atomicAdd(&ws_S[(size_t)(row + 1) * 128 + f], si1);
    atomicAdd(&ws_S[(size_t)(row + 1) * 128 + 64 + f], ci1);
    atomicAdd(&ws_S[(size_t)(row + 2) * 128 + f], si2);
    atomicAdd(&ws_S[(size_t)(row + 2) * 128 + 64 + f], ci2);
    atomicAdd(&ws_S[(size_t)(row + 3) * 128 + f], si3);
    atomicAdd(&ws_S[(size_t)(row + 3) * 128 + 64 + f], ci3);
  }
  if (!diag) {
    __syncthreads();
    #pragma unroll
    for (int k = 0; k < 8; ++k) {
      const int idx = k * 256 + tid;             // [0, 2048)
      const int j = idx >> 7, ff = idx & 127;
      atomicAdd(&ws_S[(size_t)(b * NN + J * TS + j) * 128 + ff], Sj[j][ff]);
    }
  }
}

// ---------------------------------------------------------------------------
// K3: output. One block per RPB=4 rows. ws_S is UNSCALED; mi/cnt applied at
// the write (linearity). tid<192: pe columns; tid>=192: xh embedding.
// ---------------------------------------------------------------------------
__global__ __launch_bounds__(256) void out_kernel(
    const float* __restrict__ ws_S, const float* __restrict__ ws_xc,
    const float* __restrict__ ws_cnt, const float* __restrict__ mask,
    const float* __restrict__ xh,
    const float* __restrict__ Wxh, const float* __restrict__ bxh,
    const float* __restrict__ Wp, const float* __restrict__ bp,
    float* __restrict__ out)
{
  const int blk = blockIdx.x;
  const int row0 = blk * RPB;                    // global row = b*256+i
  const int b = row0 >> 8;
  const int i0 = row0 & 255;
  const int tid = threadIdx.x;

  __shared__ __align__(16) float S_l[RPB][128];  // raw S rows
  __shared__ float ins_l[RPB][XHIN];
  __shared__ float Wxh_l[XHIN * XHHID];
  __shared__ float bxh_l[XHHID];
  __shared__ float scl_l[RPB];                   // mi/cnt
  __shared__ float bscale_l[RPB];                // mi*256/cnt
  __shared__ float mi_l[RPB];

  if (tid < 128)
    ((float4*)S_l)[tid] = ((const float4*)(ws_S + (size_t)row0 * 128))[tid];
  if (tid < 192) {
    Wxh_l[tid]       = Wxh[tid];
    Wxh_l[tid + 192] = Wxh[tid + 192];
    Wxh_l[tid + 384] = Wxh[tid + 384];
  }
  if (tid < XHHID) bxh_l[tid] = bxh[tid];
  if (tid < RPB * XHIN) {
    const int r = tid / XHIN, k = tid % XHIN;
    const int i = i0 + r;
    ins_l[r][k] = (k < 3) ? ws_xc[(b * 3 + k) * NN + i]
                          : xh[(size_t)(b * NN + i) * XHIN + k];
  }
  if (tid < RPB) {
    const float m = mask[b * NN + i0 + tid];
    const float cnt = ws_cnt[b];
    mi_l[tid] = m;
    scl_l[tid] = m / cnt;
    bscale_l[tid] = m * 256.0f / cnt;
  }
  __syncthreads();

  if (tid < POSHID) {
    const int col = tid;
    const float bpc = bp[col];
    float acc[RPB];
    #pragma unroll
    for (int r = 0; r < RPB; ++r) acc[r] = 0.f;

    #pragma unroll 8
    for (int k4 = 0; k4 < 32; ++k4) {
      const float* w = Wp + (k4 * 4) * POSHID + col;     // lanes coalesced
      const float w0 = w[0 * POSHID];
      const float w1 = w[1 * POSHID];
      const float w2 = w[2 * POSHID];
      const float w3 = w[3 * POSHID];
      #pragma unroll
      for (int r = 0; r < RPB; ++r) {
        const float4 s = ((const float4*)S_l[r])[k4];    // b128 broadcast
        acc[r] = fmaf(s.w, w3, fmaf(s.z, w2, fmaf(s.y, w1, fmaf(s.x, w0, acc[r]))));
      }
    }
    #pragma unroll
    for (int r = 0; r < RPB; ++r)
      out[(size_t)(row0 + r) * 256 + 64 + col] = acc[r] * scl_l[r] + bpc * bscale_l[r];
  } else {
    const int oo = tid - POSHID;                 // 0..63
    #pragma unroll
    for (int r = 0; r < RPB; ++r) {
      float acc = bxh_l[oo];
      #pragma unroll
      for (int k = 0; k < XHIN; ++k)
        acc = fmaf(ins_l[r][k], Wxh_l[k * XHHID + oo], acc);
      out[(size_t)(row0 + r) * 256 + oo] = acc * mi_l[r];
    }
  }
}

extern "C" void kernel_launch(void* const* d_in, const int* in_sizes, int n_in,
                              void* d_out, int out_size, void* d_ws, size_t ws_size,
                              hipStream_t stream) {
  // setup_inputs order: t, xh, node_mask, edge_mask, W_xh, b_xh, W_pos, b_pos
  const float* xh   = (const float*)d_in[1];
  const float* mask = (const float*)d_in[2];
  const float* Wxh  = (const float*)d_in[4];
  const float* bxh  = (const float*)d_in[5];
  const float* Wp   = (const float*)d_in[6];
  const float* bp   = (const float*)d_in[7];
  float* out = (float*)d_out;

  float* ws_xc  = (float*)d_ws;            // BB*3*NN floats (SoA centered x)
  float* ws_cnt = ws_xc + BB * 3 * NN;     // BB floats (+pad)
  float* ws_S   = ws_cnt + 64;             // 2048*128 floats, 16B-aligned

  mean_zero_kernel<<<BB + 64, 256, 0, stream>>>(xh, mask, ws_xc, ws_cnt,
                                                (float4*)ws_S);
  pairs_kernel<<<BB * NPAIR, 256, 0, stream>>>(ws_xc, mask, ws_S);
  out_kernel<<<BB * NN / RPB, 256, 0, stream>>>(ws_S, ws_xc, ws_cnt, mask, xh,
                                                Wxh, bxh, Wp, bp, out);
}

// Round 4
// 95.582 us; speedup vs baseline: 1.3858x; 1.3858x over previous
//
#include <hip/hip_runtime.h>
#include <math.h>

#define BB 8
#define NN 256
#define XHIN 9
#define XHHID 64
#define POSHID 192
#define TS 16                       // node tile size
#define NT (NN / TS)                // 16 tiles
#define NPAIR (NT * (NT + 1) / 2)   // 136 unordered tile-pairs
#define RPB 2                       // rows per block in out_kernel -> 1024 blocks
#define FREQC 0.10381025296523007f  // log2(100)/64

// ---------------------------------------------------------------------------
// K1: per-batch masked mean removal. One block per batch.
// (No workspace zeroing needed anymore: ws_P slots are written exactly once.)
// ---------------------------------------------------------------------------
__global__ __launch_bounds__(256) void mean_kernel(
    const float* __restrict__ xh, const float* __restrict__ mask,
    float* __restrict__ ws_xc, float* __restrict__ ws_cnt)
{
  const int b = blockIdx.x;
  const int n = threadIdx.x;

  const float* p = xh + (b * NN + n) * XHIN;
  const float x0 = p[0], x1 = p[1], x2 = p[2];
  const float m = mask[b * NN + n];

  float a0 = x0 * m, a1 = x1 * m, a2 = x2 * m, a3 = m;
  #pragma unroll
  for (int off = 32; off > 0; off >>= 1) {
    a0 += __shfl_down(a0, off, 64);
    a1 += __shfl_down(a1, off, 64);
    a2 += __shfl_down(a2, off, 64);
    a3 += __shfl_down(a3, off, 64);
  }
  __shared__ float red[4][4];
  const int lane = n & 63, wv = n >> 6;
  if (lane == 0) { red[wv][0] = a0; red[wv][1] = a1; red[wv][2] = a2; red[wv][3] = a3; }
  __syncthreads();

  const float s0 = red[0][0] + red[1][0] + red[2][0] + red[3][0];
  const float s1 = red[0][1] + red[1][1] + red[2][1] + red[3][1];
  const float s2 = red[0][2] + red[1][2] + red[2][2] + red[3][2];
  const float cnt = red[0][3] + red[1][3] + red[2][3] + red[3][3];
  const float inv = 1.0f / cnt;

  ws_xc[(b * 3 + 0) * NN + n] = (x0 - s0 * inv) * m;
  ws_xc[(b * 3 + 1) * NN + n] = (x1 - s1 * inv) * m;
  ws_xc[(b * 3 + 2) * NN + n] = (x2 - s2 * inv) * m;
  if (n == 0) ws_cnt[b] = cnt;
}

// ---------------------------------------------------------------------------
// K2: symmetric tile-pair kernel, ATOMIC-FREE. Block = (batch, pair (I,J)).
// Thread = (f = tid>>2 in [0,64), g = tid&3 owning i-rows 4g..4g+3).
// Each sin/cos at d_ij feeds row i (weight m_j, registers) AND row j
// (weight m_i, width-4 shfl_xor butterfly over the g lanes -> final value,
// no LDS/atomics). Results land in unique partial slots:
//   ws_P[((b*NT + T)*NN + i)*128 + 2f(+1)]  (sin,cos interleaved)
// where T = the OTHER tile (J for i-side, I for j-side, I for diagonal).
// Every slot is written exactly once -> no zeroing, no atomics.
// ---------------------------------------------------------------------------
__global__ __launch_bounds__(256) void pairs_kernel(
    const float* __restrict__ ws_xc, const float* __restrict__ mask,
    float* __restrict__ ws_P)
{
  const int b = blockIdx.x / NPAIR;
  int p = blockIdx.x % NPAIR;
  int I = 0;
  while (p >= NT - I) { p -= NT - I; ++I; }      // uniform, <=16 iters
  const int J = I + p;
  const bool diag = (I == J);
  const int tid = threadIdx.x;

  __shared__ float xs[2][3][TS];                 // coords of tile I(0)/J(1)
  __shared__ float msk[2][TS];                   // masks
  __shared__ __align__(16) float d_s[TS][TS];    // [j][i]

  if (tid < 96) {
    const int t = tid / 48, r = tid % 48, c = r / 16, n = r % 16;
    xs[t][c][n] = ws_xc[(b * 3 + c) * NN + (t ? J : I) * TS + n];
  }
  if (tid < 32) {
    const int t = tid >> 4, n = tid & 15;
    msk[t][n] = mask[b * NN + (t ? J : I) * TS + n];
  }
  __syncthreads();
  {
    const int i = tid & 15, j = tid >> 4;        // one cell per thread
    const float dx = xs[0][0][i] - xs[1][0][j];
    const float dy = xs[0][1][i] - xs[1][1][j];
    const float dz = xs[0][2][i] - xs[1][2][j];
    d_s[j][i] = sqrtf(fmaf(dx, dx, fmaf(dy, dy, dz * dz)) + 1e-12f);
  }
  __syncthreads();

  const int g = tid & 3;                         // row-group (adjacent lanes!)
  const int f = tid >> 2;                        // freq 0..63
  const float freq = __builtin_exp2f((float)f * FREQC);  // 100^(f/64)

  float si0 = 0.f, si1 = 0.f, si2 = 0.f, si3 = 0.f;
  float ci0 = 0.f, ci1 = 0.f, ci2 = 0.f, ci3 = 0.f;
  float js0, js1, js2, js3, jc0, jc1, jc2, jc3;
  const float mA0 = msk[0][g * 4 + 0], mA1 = msk[0][g * 4 + 1];
  const float mA2 = msk[0][g * 4 + 2], mA3 = msk[0][g * 4 + 3];

  #pragma unroll
  for (int j = 0; j < TS; ++j) {
    const float4 d4 = *(const float4*)&d_s[j][g * 4];    // b128 broadcast
    const float mj = msk[1][j];
    const float r0 = __builtin_amdgcn_fractf(d4.x * freq);
    const float r1 = __builtin_amdgcn_fractf(d4.y * freq);
    const float r2 = __builtin_amdgcn_fractf(d4.z * freq);
    const float r3 = __builtin_amdgcn_fractf(d4.w * freq);
    const float s0 = __builtin_amdgcn_sinf(r0), c0 = __builtin_amdgcn_cosf(r0);
    const float s1 = __builtin_amdgcn_sinf(r1), c1 = __builtin_amdgcn_cosf(r1);
    const float s2 = __builtin_amdgcn_sinf(r2), c2 = __builtin_amdgcn_cosf(r2);
    const float s3 = __builtin_amdgcn_sinf(r3), c3 = __builtin_amdgcn_cosf(r3);
    si0 = fmaf(mj, s0, si0); ci0 = fmaf(mj, c0, ci0);
    si1 = fmaf(mj, s1, si1); ci1 = fmaf(mj, c1, ci1);
    si2 = fmaf(mj, s2, si2); ci2 = fmaf(mj, c2, ci2);
    si3 = fmaf(mj, s3, si3); ci3 = fmaf(mj, c3, ci3);

    // j-side: sum over this thread's 4 i-rows, then butterfly over g lanes
    float sj = fmaf(mA0, s0, fmaf(mA1, s1, fmaf(mA2, s2, mA3 * s3)));
    float cj = fmaf(mA0, c0, fmaf(mA1, c1, fmaf(mA2, c2, mA3 * c3)));
    sj += __shfl_xor(sj, 1, 64); sj += __shfl_xor(sj, 2, 64);
    cj += __shfl_xor(cj, 1, 64); cj += __shfl_xor(cj, 2, 64);
    // thread keeps j's total iff (j&3)==g  (static j -> cndmask, static idx)
    if ((j & 3) == g) {
      const int u = j >> 2;
      if (u == 0) { js0 = sj; jc0 = cj; }
      else if (u == 1) { js1 = sj; jc1 = cj; }
      else if (u == 2) { js2 = sj; jc2 = cj; }
      else { js3 = sj; jc3 = cj; }
    }
  }

  // i-side partials: slot T=J, rows I*TS + 4g + r, element f (interleaved)
  {
    float2* dst = (float2*)(ws_P +
        ((size_t)(b * NT + J) * NN + I * TS + g * 4) * 128);
    dst[0 * 64 + f] = make_float2(si0, ci0);
    dst[1 * 64 + f] = make_float2(si1, ci1);
    dst[2 * 64 + f] = make_float2(si2, ci2);
    dst[3 * 64 + f] = make_float2(si3, ci3);
  }
  // j-side partials: slot T=I, rows J*TS + (4u+g)
  if (!diag) {
    float2* dst = (float2*)(ws_P +
        ((size_t)(b * NT + I) * NN + J * TS) * 128);
    dst[(size_t)(4 * 0 + g) * 64 + f] = make_float2(js0, jc0);
    dst[(size_t)(4 * 1 + g) * 64 + f] = make_float2(js1, jc1);
    dst[(size_t)(4 * 2 + g) * 64 + f] = make_float2(js2, jc2);
    dst[(size_t)(4 * 3 + g) * 64 + f] = make_float2(js3, jc3);
  }
}

// ---------------------------------------------------------------------------
// K3: output + slot-reduction. One block per RPB=2 rows (1024 blocks).
// Stage: S_l[r][k] = sum over 16 slots of ws_P (interleaved order: k=2f sin,
// 2f+1 cos). Dot loop walks interleaved S with permuted Wp rows (same load
// count). tid<192: pe columns (2 rows); tid>=192: xh embedding (2 rows).
// ---------------------------------------------------------------------------
__global__ __launch_bounds__(256) void out_kernel(
    const float* __restrict__ ws_P, const float* __restrict__ ws_xc,
    const float* __restrict__ ws_cnt, const float* __restrict__ mask,
    const float* __restrict__ xh,
    const float* __restrict__ Wxh, const float* __restrict__ bxh,
    const float* __restrict__ Wp, const float* __restrict__ bp,
    float* __restrict__ out)
{
  const int blk = blockIdx.x;
  const int row0 = blk * RPB;                    // global row = b*256+i
  const int b = row0 >> 8;
  const int i0 = row0 & 255;
  const int tid = threadIdx.x;

  __shared__ __align__(16) float S_l[RPB][128];  // interleaved reduced S
  __shared__ float ins_l[RPB][XHIN];
  __shared__ float Wxh_l[XHIN * XHHID];
  __shared__ float bxh_l[XHHID];
  __shared__ float scl_l[RPB];                   // mi/cnt
  __shared__ float bscale_l[RPB];                // mi*256/cnt
  __shared__ float mi_l[RPB];

  // reduce 16 partial slots: thread (r = tid>>7, c = tid&127)
  {
    const int r = tid >> 7, c = tid & 127;
    const int i = i0 + r;
    const float* src = ws_P + (size_t)b * NT * NN * 128 + (size_t)i * 128 + c;
    float s = 0.f;
    #pragma unroll
    for (int T = 0; T < NT; ++T)
      s += src[(size_t)T * NN * 128];            // coalesced per T
    S_l[r][c] = s;
  }
  if (tid < 192) {
    Wxh_l[tid]       = Wxh[tid];
    Wxh_l[tid + 192] = Wxh[tid + 192];
    Wxh_l[tid + 384] = Wxh[tid + 384];
  }
  if (tid < XHHID) bxh_l[tid] = bxh[tid];
  if (tid < RPB * XHIN) {
    const int r = tid / XHIN, k = tid % XHIN;
    const int i = i0 + r;
    ins_l[r][k] = (k < 3) ? ws_xc[(b * 3 + k) * NN + i]
                          : xh[(size_t)(b * NN + i) * XHIN + k];
  }
  if (tid < RPB) {
    const float m = mask[b * NN + i0 + tid];
    const float cnt = ws_cnt[b];
    mi_l[tid] = m;
    scl_l[tid] = m / cnt;
    bscale_l[tid] = m * 256.0f / cnt;
  }
  __syncthreads();

  if (tid < POSHID) {
    const int col = tid;
    const float bpc = bp[col];
    float acc0 = 0.f, acc1 = 0.f;

    #pragma unroll 8
    for (int u = 0; u < 32; ++u) {
      // interleaved chunk 4u..4u+3 -> Wp rows {2u, 64+2u, 2u+1, 64+2u+1}
      const float4 s0 = ((const float4*)S_l[0])[u];
      const float4 s1 = ((const float4*)S_l[1])[u];
      const float* wA = Wp + (2 * u) * POSHID + col;
      const float* wB = Wp + (64 + 2 * u) * POSHID + col;
      const float w0 = wA[0];
      const float w1 = wB[0];
      const float w2 = wA[POSHID];
      const float w3 = wB[POSHID];
      acc0 = fmaf(s0.w, w3, fmaf(s0.z, w2, fmaf(s0.y, w1, fmaf(s0.x, w0, acc0))));
      acc1 = fmaf(s1.w, w3, fmaf(s1.z, w2, fmaf(s1.y, w1, fmaf(s1.x, w0, acc1))));
    }
    out[(size_t)(row0 + 0) * 256 + 64 + col] = acc0 * scl_l[0] + bpc * bscale_l[0];
    out[(size_t)(row0 + 1) * 256 + 64 + col] = acc1 * scl_l[1] + bpc * bscale_l[1];
  } else {
    const int oo = tid - POSHID;                 // 0..63
    #pragma unroll
    for (int r = 0; r < RPB; ++r) {
      float acc = bxh_l[oo];
      #pragma unroll
      for (int k = 0; k < XHIN; ++k)
        acc = fmaf(ins_l[r][k], Wxh_l[k * XHHID + oo], acc);
      out[(size_t)(row0 + r) * 256 + oo] = acc * mi_l[r];
    }
  }
}

extern "C" void kernel_launch(void* const* d_in, const int* in_sizes, int n_in,
                              void* d_out, int out_size, void* d_ws, size_t ws_size,
                              hipStream_t stream) {
  // setup_inputs order: t, xh, node_mask, edge_mask, W_xh, b_xh, W_pos, b_pos
  const float* xh   = (const float*)d_in[1];
  const float* mask = (const float*)d_in[2];
  const float* Wxh  = (const float*)d_in[4];
  const float* bxh  = (const float*)d_in[5];
  const float* Wp   = (const float*)d_in[6];
  const float* bp   = (const float*)d_in[7];
  float* out = (float*)d_out;

  float* ws_xc  = (float*)d_ws;            // BB*3*NN floats (SoA centered x)
  float* ws_cnt = ws_xc + BB * 3 * NN;     // BB floats (+pad)
  float* ws_P   = ws_cnt + 64;             // BB*NT*NN*128 floats = 16.8 MB

  mean_kernel<<<BB, 256, 0, stream>>>(xh, mask, ws_xc, ws_cnt);
  pairs_kernel<<<BB * NPAIR, 256, 0, stream>>>(ws_xc, mask, ws_P);
  out_kernel<<<BB * NN / RPB, 256, 0, stream>>>(ws_P, ws_xc, ws_cnt, mask, xh,
                                                Wxh, bxh, Wp, bp, out);
}

// Round 5
// 81.766 us; speedup vs baseline: 1.6200x; 1.1690x over previous
//
#include <hip/hip_runtime.h>
#include <math.h>

#define BB 8
#define NN 256
#define XHIN 9
#define XHHID 64
#define POSHID 192
#define FREQC 0.10381025296523007f  // log2(100)/64

// ---------------------------------------------------------------------------
// Single fused kernel. One block per (b,i) output row; 2048 blocks, 256 thr.
// Each block redundantly computes the per-batch masked mean (same shfl+LDS
// tree as the old mean_kernel -> bit-identical), centers x in LDS, then runs
// the proven R2 pipeline: distances -> 2-freq sin/cos accumulation -> S ->
// {pe GEMV (192 thr) || xh embedding (64 thr)}. No workspace, no atomics,
// ONE dispatch (dispatch count is the measured dominant cost: R1-R4 ledger).
// ---------------------------------------------------------------------------
__global__ __launch_bounds__(256) void fused_kernel(
    const float* __restrict__ xh, const float* __restrict__ mask,
    const float* __restrict__ Wxh, const float* __restrict__ bxh,
    const float* __restrict__ Wp, const float* __restrict__ bp,
    float* __restrict__ out)
{
  const int blk = blockIdx.x;
  const int b = blk >> 8;
  const int i = blk & 255;
  const int tid = threadIdx.x;

  __shared__ float red[4][4];
  __shared__ float xs[3][NN];                    // centered x (SoA)
  __shared__ float2 dm_s[NN];                    // (dist, mask_j)
  __shared__ __align__(16) float part[8][128];   // [jg][sin 0..63 | cos 64..127]
  __shared__ __align__(16) float Ssc[128];
  __shared__ float ins_s[XHIN];                  // [xc_i(3), h_i(6)]

  // ---- phase 0: per-batch masked mean, computed per block (bit-identical
  // tree to the old mean_kernel: wave shfl reduce -> red[][] -> sum) ----
  const float* p = xh + (b * NN + tid) * XHIN;
  const float x0 = p[0], x1 = p[1], x2 = p[2];
  const float m = mask[b * NN + tid];

  float a0 = x0 * m, a1 = x1 * m, a2 = x2 * m, a3 = m;
  #pragma unroll
  for (int off = 32; off > 0; off >>= 1) {
    a0 += __shfl_down(a0, off, 64);
    a1 += __shfl_down(a1, off, 64);
    a2 += __shfl_down(a2, off, 64);
    a3 += __shfl_down(a3, off, 64);
  }
  const int lane = tid & 63, wv = tid >> 6;
  if (lane == 0) { red[wv][0] = a0; red[wv][1] = a1; red[wv][2] = a2; red[wv][3] = a3; }
  __syncthreads();

  const float s0 = red[0][0] + red[1][0] + red[2][0] + red[3][0];
  const float s1 = red[0][1] + red[1][1] + red[2][1] + red[3][1];
  const float s2 = red[0][2] + red[1][2] + red[2][2] + red[3][2];
  const float cnt = red[0][3] + red[1][3] + red[2][3] + red[3][3];
  const float inv = 1.0f / cnt;

  const float xc0 = (x0 - s0 * inv) * m;
  const float xc1 = (x1 - s1 * inv) * m;
  const float xc2 = (x2 - s2 * inv) * m;
  xs[0][tid] = xc0; xs[1][tid] = xc1; xs[2][tid] = xc2;
  __syncthreads();

  // ---- phase 1: distances vs row i (row-i coords broadcast from LDS) ----
  {
    const float dx = xs[0][i] - xc0;
    const float dy = xs[1][i] - xc1;
    const float dz = xs[2][i] - xc2;
    const float sq = fmaf(dx, dx, fmaf(dy, dy, dz * dz));
    dm_s[tid] = make_float2(sqrtf(sq + 1e-12f), m);
  }
  if (tid < XHIN)
    ins_s[tid] = (tid < 3) ? xs[tid][i] : xh[(b * NN + i) * XHIN + tid];
  __syncthreads();

  // ---- phase 2: two freqs per thread over 32 j's (R2 structure) ----
  const int fp = tid & 31, jg = tid >> 5;
  const float f0 = (float)(2 * fp);
  const float freq0 = __builtin_exp2f(f0 * FREQC);          // 100^(f/64)
  const float freq1 = __builtin_exp2f((f0 + 1.0f) * FREQC);
  float ss0 = 0.f, cc0 = 0.f, ss1 = 0.f, cc1 = 0.f;
  const float2* dmp = dm_s + jg * 32;
  #pragma unroll 8
  for (int u = 0; u < 32; ++u) {
    const float2 dm = dmp[u];                    // one b64 broadcast / 2 cells
    const float r0 = __builtin_amdgcn_fractf(dm.x * freq0);  // revolutions
    const float r1 = __builtin_amdgcn_fractf(dm.x * freq1);
    ss0 = fmaf(__builtin_amdgcn_sinf(r0), dm.y, ss0);
    cc0 = fmaf(__builtin_amdgcn_cosf(r0), dm.y, cc0);
    ss1 = fmaf(__builtin_amdgcn_sinf(r1), dm.y, ss1);
    cc1 = fmaf(__builtin_amdgcn_cosf(r1), dm.y, cc1);
  }
  *(float2*)&part[jg][2 * fp]      = make_float2(ss0, ss1);
  *(float2*)&part[jg][64 + 2 * fp] = make_float2(cc0, cc1);
  __syncthreads();

  const float mi = dm_s[i].y;                    // mask_i (staged)
  if (tid < 128) {
    float s = part[0][tid];
    #pragma unroll
    for (int g = 1; g < 8; ++g) s += part[g][tid];
    Ssc[tid] = s * (mi / cnt);
  }
  __syncthreads();

  if (tid < POSHID) {
    // ---- phase 3a: 192 pe outputs, 128-MAC dot; Ssc via b128 broadcasts ----
    const float4* S4 = (const float4*)Ssc;
    float acc = bp[tid] * (mi * 256.0f / cnt);
    #pragma unroll 8
    for (int k4 = 0; k4 < 32; ++k4) {
      const float4 s = S4[k4];
      const float* w = Wp + (k4 * 4) * POSHID + tid;
      acc = fmaf(s.x, w[0 * POSHID], acc);
      acc = fmaf(s.y, w[1 * POSHID], acc);
      acc = fmaf(s.z, w[2 * POSHID], acc);
      acc = fmaf(s.w, w[3 * POSHID], acc);
    }
    out[(size_t)(b * NN + i) * 256 + 64 + tid] = acc;
  } else {
    // ---- phase 3b (concurrent): 64 xh-embedding outputs ----
    const int oo = tid - POSHID;                 // 0..63
    float acc = bxh[oo];
    #pragma unroll
    for (int k = 0; k < XHIN; ++k)
      acc = fmaf(ins_s[k], Wxh[k * XHHID + oo], acc);
    out[(size_t)(b * NN + i) * 256 + oo] = acc * mi;
  }
}

extern "C" void kernel_launch(void* const* d_in, const int* in_sizes, int n_in,
                              void* d_out, int out_size, void* d_ws, size_t ws_size,
                              hipStream_t stream) {
  // setup_inputs order: t, xh, node_mask, edge_mask, W_xh, b_xh, W_pos, b_pos
  const float* xh   = (const float*)d_in[1];
  const float* mask = (const float*)d_in[2];
  const float* Wxh  = (const float*)d_in[4];
  const float* bxh  = (const float*)d_in[5];
  const float* Wp   = (const float*)d_in[6];
  const float* bp   = (const float*)d_in[7];
  float* out = (float*)d_out;

  fused_kernel<<<BB * NN, 256, 0, stream>>>(xh, mask, Wxh, bxh, Wp, bp, out);
}

// Round 6
// 80.347 us; speedup vs baseline: 1.6486x; 1.0177x over previous
//
#include <hip/hip_runtime.h>
#include <math.h>

#define BB 8
#define NN 256
#define XHIN 9
#define XHHID 64
#define POSHID 192
#define FREQC 0.10381025296523007f  // log2(100)/64

// ---------------------------------------------------------------------------
// Single fused kernel, RPB=2: one block per TWO output rows (i0=2q, i0+1).
// 1024 blocks x 256 threads (4 blocks/CU, 4 waves/SIMD). vs R5: Wp L2
// traffic halved (each Wp load feeds 2 rows' fmas), per-row fixed work
// (mean redundancy, staging, barriers) halved, trans work conserved.
// Per-row math order is bit-identical to R5 (absmax must stay 0.0078125).
// ---------------------------------------------------------------------------
__global__ __launch_bounds__(256) void fused_kernel(
    const float* __restrict__ xh, const float* __restrict__ mask,
    const float* __restrict__ Wxh, const float* __restrict__ bxh,
    const float* __restrict__ Wp, const float* __restrict__ bp,
    float* __restrict__ out)
{
  const int blk = blockIdx.x;
  const int b = blk >> 7;
  const int i0 = (blk & 127) * 2;                // rows i0, i0+1
  const int tid = threadIdx.x;

  __shared__ float red[4][4];
  __shared__ float xs[3][NN];                    // centered x (SoA)
  __shared__ float2 dm_s[2][NN];                 // per row: (dist, mask_j)
  __shared__ __align__(16) float part[8][2][128];// [jg][row][sin|cos]
  __shared__ __align__(16) float Ssc[2][128];
  __shared__ float ins_s[2][XHIN];               // per row: [xc(3), h(6)]

  // ---- phase 0: per-batch masked mean (bit-identical tree) ----
  const float* p = xh + (b * NN + tid) * XHIN;
  const float x0 = p[0], x1 = p[1], x2 = p[2];
  const float m = mask[b * NN + tid];

  float a0 = x0 * m, a1 = x1 * m, a2 = x2 * m, a3 = m;
  #pragma unroll
  for (int off = 32; off > 0; off >>= 1) {
    a0 += __shfl_down(a0, off, 64);
    a1 += __shfl_down(a1, off, 64);
    a2 += __shfl_down(a2, off, 64);
    a3 += __shfl_down(a3, off, 64);
  }
  const int lane = tid & 63, wv = tid >> 6;
  if (lane == 0) { red[wv][0] = a0; red[wv][1] = a1; red[wv][2] = a2; red[wv][3] = a3; }
  __syncthreads();

  const float s0 = red[0][0] + red[1][0] + red[2][0] + red[3][0];
  const float s1 = red[0][1] + red[1][1] + red[2][1] + red[3][1];
  const float s2 = red[0][2] + red[1][2] + red[2][2] + red[3][2];
  const float cnt = red[0][3] + red[1][3] + red[2][3] + red[3][3];
  const float inv = 1.0f / cnt;

  const float xc0 = (x0 - s0 * inv) * m;
  const float xc1 = (x1 - s1 * inv) * m;
  const float xc2 = (x2 - s2 * inv) * m;
  xs[0][tid] = xc0; xs[1][tid] = xc1; xs[2][tid] = xc2;
  __syncthreads();

  // ---- phase 1: distances of every j (=tid) to rows i0 and i0+1 ----
  {
    const float dx0 = xs[0][i0] - xc0, dx1 = xs[0][i0 + 1] - xc0;
    const float dy0 = xs[1][i0] - xc1, dy1 = xs[1][i0 + 1] - xc1;
    const float dz0 = xs[2][i0] - xc2, dz1 = xs[2][i0 + 1] - xc2;
    const float q0 = fmaf(dx0, dx0, fmaf(dy0, dy0, dz0 * dz0));
    const float q1 = fmaf(dx1, dx1, fmaf(dy1, dy1, dz1 * dz1));
    dm_s[0][tid] = make_float2(sqrtf(q0 + 1e-12f), m);
    dm_s[1][tid] = make_float2(sqrtf(q1 + 1e-12f), m);
  }
  if (tid < 2 * XHIN) {
    const int r = tid / XHIN, k = tid % XHIN;
    ins_s[r][k] = (k < 3) ? xs[k][i0 + r]
                          : xh[(b * NN + i0 + r) * XHIN + k];
  }
  __syncthreads();

  // ---- phase 2: two freqs per thread, 32 j's, BOTH rows ----
  const int fp = tid & 31, jg = tid >> 5;
  const float f0 = (float)(2 * fp);
  const float freq0 = __builtin_exp2f(f0 * FREQC);          // 100^(f/64)
  const float freq1 = __builtin_exp2f((f0 + 1.0f) * FREQC);
  float As0 = 0.f, Ac0 = 0.f, As1 = 0.f, Ac1 = 0.f;         // row i0
  float Bs0 = 0.f, Bc0 = 0.f, Bs1 = 0.f, Bc1 = 0.f;         // row i0+1
  const float2* dA = dm_s[0] + jg * 32;
  const float2* dB = dm_s[1] + jg * 32;
  #pragma unroll 8
  for (int u = 0; u < 32; ++u) {
    const float2 da = dA[u];                     // b64 broadcast
    const float2 db = dB[u];
    const float ra0 = __builtin_amdgcn_fractf(da.x * freq0);
    const float ra1 = __builtin_amdgcn_fractf(da.x * freq1);
    const float rb0 = __builtin_amdgcn_fractf(db.x * freq0);
    const float rb1 = __builtin_amdgcn_fractf(db.x * freq1);
    As0 = fmaf(__builtin_amdgcn_sinf(ra0), da.y, As0);
    Ac0 = fmaf(__builtin_amdgcn_cosf(ra0), da.y, Ac0);
    As1 = fmaf(__builtin_amdgcn_sinf(ra1), da.y, As1);
    Ac1 = fmaf(__builtin_amdgcn_cosf(ra1), da.y, Ac1);
    Bs0 = fmaf(__builtin_amdgcn_sinf(rb0), db.y, Bs0);
    Bc0 = fmaf(__builtin_amdgcn_cosf(rb0), db.y, Bc0);
    Bs1 = fmaf(__builtin_amdgcn_sinf(rb1), db.y, Bs1);
    Bc1 = fmaf(__builtin_amdgcn_cosf(rb1), db.y, Bc1);
  }
  *(float2*)&part[jg][0][2 * fp]      = make_float2(As0, As1);
  *(float2*)&part[jg][0][64 + 2 * fp] = make_float2(Ac0, Ac1);
  *(float2*)&part[jg][1][2 * fp]      = make_float2(Bs0, Bs1);
  *(float2*)&part[jg][1][64 + 2 * fp] = make_float2(Bc0, Bc1);
  __syncthreads();

  // ---- reduce partials: thread (r = tid>>7, c = tid&127) ----
  {
    const int r = tid >> 7, c = tid & 127;
    const float mir = dm_s[0][i0 + r].y;         // mask_i for this row
    float s = part[0][r][c];
    #pragma unroll
    for (int g = 1; g < 8; ++g) s += part[g][r][c];
    Ssc[r][c] = s * (mir / cnt);
  }
  __syncthreads();

  if (tid < POSHID) {
    // ---- phase 3a: pe GEMV, both rows share each Wp load ----
    const int col = tid;
    const float mi0 = dm_s[0][i0 + 0].y;
    const float mi1 = dm_s[0][i0 + 1].y;
    const float bpc = bp[col];
    float acc0 = bpc * (mi0 * 256.0f / cnt);
    float acc1 = bpc * (mi1 * 256.0f / cnt);
    const float4* S40 = (const float4*)Ssc[0];
    const float4* S41 = (const float4*)Ssc[1];
    #pragma unroll 8
    for (int k4 = 0; k4 < 32; ++k4) {
      const float* w = Wp + (k4 * 4) * POSHID + col;
      const float w0 = w[0 * POSHID];
      const float w1 = w[1 * POSHID];
      const float w2 = w[2 * POSHID];
      const float w3 = w[3 * POSHID];
      const float4 sa = S40[k4];                 // b128 broadcast
      const float4 sb = S41[k4];
      acc0 = fmaf(sa.w, w3, fmaf(sa.z, w2, fmaf(sa.y, w1, fmaf(sa.x, w0, acc0))));
      acc1 = fmaf(sb.w, w3, fmaf(sb.z, w2, fmaf(sb.y, w1, fmaf(sb.x, w0, acc1))));
    }
    out[(size_t)(b * NN + i0 + 0) * 256 + 64 + col] = acc0;
    out[(size_t)(b * NN + i0 + 1) * 256 + 64 + col] = acc1;
  } else {
    // ---- phase 3b (concurrent): xh embedding, both rows ----
    const int oo = tid - POSHID;                 // 0..63
    #pragma unroll
    for (int r = 0; r < 2; ++r) {
      const float mir = dm_s[0][i0 + r].y;
      float acc = bxh[oo];
      #pragma unroll
      for (int k = 0; k < XHIN; ++k)
        acc = fmaf(ins_s[r][k], Wxh[k * XHHID + oo], acc);
      out[(size_t)(b * NN + i0 + r) * 256 + oo] = acc * mir;
    }
  }
}

extern "C" void kernel_launch(void* const* d_in, const int* in_sizes, int n_in,
                              void* d_out, int out_size, void* d_ws, size_t ws_size,
                              hipStream_t stream) {
  // setup_inputs order: t, xh, node_mask, edge_mask, W_xh, b_xh, W_pos, b_pos
  const float* xh   = (const float*)d_in[1];
  const float* mask = (const float*)d_in[2];
  const float* Wxh  = (const float*)d_in[4];
  const float* bxh  = (const float*)d_in[5];
  const float* Wp   = (const float*)d_in[6];
  const float* bp   = (const float*)d_in[7];
  float* out = (float*)d_out;

  fused_kernel<<<BB * NN / 2, 256, 0, stream>>>(xh, mask, Wxh, bxh, Wp, bp, out);
}